// Round 7
// baseline (203.441 us; speedup 1.0000x reference)
//
#include <hip/hip_runtime.h>
#include <hip/hip_bf16.h>
#include <stdint.h>
#include <math.h>

// Problem constants (fixed by setup_inputs)
#define BATCH 8192   // B rows of embeddings
#define DIM   2048   // D feature dim
#define KDIR  512    // K directions
#define NPTS  17     // quadrature points

typedef _Float16 half8  __attribute__((ext_vector_type(8)));
typedef float   floatx4 __attribute__((ext_vector_type(4)));

#define AS1 __attribute__((address_space(1)))
#define AS3 __attribute__((address_space(3)))

// async global->LDS, 16B per lane. LDS dest is wave-uniform base + lane*16;
// the per-lane GLOBAL address is free -> use it to swizzle LDS chunk order.
__device__ __forceinline__ void g2l16(const void* g, void* l) {
    __builtin_amdgcn_global_load_lds((AS1 void*)(uintptr_t)g, (AS3 void*)l, 16u, 0, 0u);
}

// ---------------------------------------------------------------------------
// K1: fused normalize + transpose (+ zero pp/out in low blocks).
__global__ __launch_bounds__(256) void norm_dT(const float* __restrict__ dir,
                                               _Float16* __restrict__ dT,
                                               float* __restrict__ pp,
                                               float* __restrict__ out) {
    const int k = blockIdx.x;
    const int t = threadIdx.x;
    if (k < 4) pp[k * 256 + t] = 0.f;
    if (k == 4 && t == 0) out[0] = 0.f;

    float v[8];
    float s = 0.f;
    #pragma unroll
    for (int i = 0; i < 8; ++i) {
        v[i] = dir[(size_t)(t * 8 + i) * KDIR + k];
        s = fmaf(v[i], v[i], s);
    }
    for (int off = 32; off > 0; off >>= 1) s += __shfl_down(s, off, 64);
    __shared__ float ws_[4];
    if ((t & 63) == 0) ws_[t >> 6] = s;
    __syncthreads();
    const float inv = 1.0f / fmaxf(sqrtf(ws_[0] + ws_[1] + ws_[2] + ws_[3]), 1e-12f);
    half8 h;
    #pragma unroll
    for (int i = 0; i < 8; ++i) h[i] = (_Float16)(v[i] * inv);
    *(half8*)(dT + (size_t)k * DIM + t * 8) = h;
}

// ---------------------------------------------------------------------------
// K2: MFMA GEMM with A staged as FP32 straight from emb (cvt pass fused away).
// 128x128 tile, BK=32, double-buffered (sA fp32 2x16KB + sB fp16 2x8KB = 48KB).
// A-chunk XOR swizzle (chunk cc of row m holds global chunk cc^(m&7)) breaks
// the 128B-row bank degeneracy; frag reads are 2 ds_read_b128 + 8 v_cvt.
// Pipeline: R6's ISSUE->vmcnt(6)->barrier->compute->lgkm->barrier shape.
// Epilogue: plain C stores + fused column sum/sumsq atomics into pp[1024].
__global__ __launch_bounds__(256) void gemm16(const float* __restrict__ A,
                                              const _Float16* __restrict__ Bt,
                                              float* __restrict__ C,
                                              float* __restrict__ pp) {
    __shared__ float    sA[2][128 * 32];   // [stage][m][k-chunk swizzled] 16KB
    __shared__ _Float16 sB[2][128 * 32];   // [stage][m][k] 64B rows (proven)

    const int tid  = threadIdx.x;
    const int lane = tid & 63;
    const int wave = tid >> 6;
    const int wm = wave & 1;
    const int wn = wave >> 1;
    const int tm = blockIdx.x * 128;
    const int tn = blockIdx.y * 128;

#define ISSUE(IT, ST)                                                          \
    do {                                                                       \
        _Pragma("unroll")                                                      \
        for (int r = 0; r < 4; ++r) {   /* A: 4 rounds of 4KB */               \
            const int p  = tid + 256 * r;                                      \
            const int m  = p >> 3;                                             \
            const int j  = (p & 7) ^ (m & 7);                                  \
            g2l16(A + (size_t)(tm + m) * DIM + (IT) * 32 + j * 4,              \
                  (char*)&sA[ST][0] + r * 4096 + tid * 16);                    \
        }                                                                      \
        _Pragma("unroll")                                                      \
        for (int r = 0; r < 2; ++r) {   /* B: 2 rounds of 4KB */               \
            const int p  = tid + 256 * r;                                      \
            const int m  = p >> 2;                                             \
            const int c  = p & 3;                                              \
            g2l16(Bt + (size_t)(tn + m) * DIM + (IT) * 32 + c * 8,             \
                  (char*)&sB[ST][0] + r * 4096 + tid * 16);                    \
        }                                                                      \
    } while (0)

    const floatx4 zero = {0.f, 0.f, 0.f, 0.f};
    floatx4 acc[4][4];
    #pragma unroll
    for (int i = 0; i < 4; ++i)
        #pragma unroll
        for (int j = 0; j < 4; ++j) acc[i][j] = zero;

    const int mrow = lane & 15;          // operand free index
    const int quad = lane >> 4;
    const int kk   = quad * 8;           // k offset (elems), 0/8/16/24

    ISSUE(0, 0);

    const int NIT = DIM / 32;            // 64
    for (int it = 0; it < NIT; ++it) {
        const int s = it & 1;
        if (it + 1 < NIT) {
            ISSUE(it + 1, (it + 1) & 1);
            asm volatile("s_waitcnt vmcnt(6)" ::: "memory");  // stage it landed
        } else {
            asm volatile("s_waitcnt vmcnt(0)" ::: "memory");
        }
        asm volatile("s_barrier" ::: "memory");

        half8 af[4], bf[4];
        #pragma unroll
        for (int f = 0; f < 4; ++f) {
            const int m_op = wm * 64 + f * 16 + mrow;
            const int jc   = quad * 2;                    // fp32 chunk of kk
            const char* rb = (const char*)&sA[s][0] + m_op * 128;
            floatx4 lo = *(const floatx4*)(rb + ((jc     ^ (m_op & 7)) * 16));
            floatx4 hi = *(const floatx4*)(rb + (((jc+1) ^ (m_op & 7)) * 16));
            half8 h;
            #pragma unroll
            for (int e = 0; e < 4; ++e) {
                h[e]     = (_Float16)lo[e];
                h[e + 4] = (_Float16)hi[e];
            }
            af[f] = h;
            bf[f] = *(const half8*)(&sB[s][(size_t)(wn * 64 + f * 16 + mrow) * 32 + kk]);
        }
        #pragma unroll
        for (int i = 0; i < 4; ++i)
            #pragma unroll
            for (int j = 0; j < 4; ++j)
                acc[i][j] = __builtin_amdgcn_mfma_f32_16x16x32_f16(af[i], bf[j], acc[i][j], 0, 0, 0);

        asm volatile("s_waitcnt lgkmcnt(0)" ::: "memory");
        asm volatile("s_barrier" ::: "memory");
    }
#undef ISSUE

    // C/D layout: col = lane&15, row = (lane>>4)*4 + reg
    const int r0 = (lane >> 4) * 4;
    const int cn = lane & 15;
    #pragma unroll
    for (int i = 0; i < 4; ++i) {
        #pragma unroll
        for (int j = 0; j < 4; ++j) {
            const int row = tm + wm * 64 + i * 16 + r0;
            const int col = tn + wn * 64 + j * 16 + cn;
            #pragma unroll
            for (int r = 0; r < 4; ++r)
                C[(size_t)(row + r) * KDIR + col] = acc[i][j][r];
        }
    }

    // fused column stats: reduce across quads, 16 lanes atomic per frag-col.
    #pragma unroll
    for (int j = 0; j < 4; ++j) {
        float s = 0.f, q = 0.f;
        #pragma unroll
        for (int i = 0; i < 4; ++i)
            #pragma unroll
            for (int r = 0; r < 4; ++r) {
                float v = acc[i][j][r];
                s += v;
                q = fmaf(v, v, q);
            }
        s += __shfl_down(s, 32, 64); q += __shfl_down(q, 32, 64);
        s += __shfl_down(s, 16, 64); q += __shfl_down(q, 16, 64);
        if (lane < 16) {
            const int col = tn + wn * 64 + j * 16 + lane;
            atomicAdd(&pp[col], s);
            atomicAdd(&pp[KDIR + col], q);
        }
    }
}

// ---------------------------------------------------------------------------
// K3: ECF partials; mu/isd inline from pp. 32 rows/chunk -> 256 chunks x 2
// halves = 512 blocks. Angle-addition recurrence (measured-pass numerics).
__global__ __launch_bounds__(256) void ecf_p1(const float* __restrict__ proj,
                                              const float* __restrict__ pp,
                                              float* __restrict__ pecf) {
    const int ch = blockIdx.x >> 1;                      // 0..255
    const int c  = (blockIdx.x & 1) * 256 + threadIdx.x; // 0..511
    const double s_  = (double)pp[c];
    const double s2_ = (double)pp[KDIR + c];
    const double mm  = s_ / (double)BATCH;
    const double var = (s2_ - (double)BATCH * mm * mm) / (double)(BATCH - 1);
    const float m   = (float)mm;
    const float sdi = (float)(1.0 / (sqrt(var) + 1e-8));

    float cr[NPTS], ci[NPTS];
    #pragma unroll
    for (int i = 0; i < NPTS; ++i) { cr[i] = 0.f; ci[i] = 0.f; }
    const float* p = proj + (size_t)(ch * 32) * KDIR + c;
    #pragma unroll 8
    for (int r = 0; r < 32; ++r) {
        float z = (p[(size_t)r * KDIR] - m) * sdi;
        float a = z * (2.0f / 17.0f);                    // t_1 * z
        float s1, c1;
        __sincosf(a, &s1, &c1);
        float ck = c1, sk = s1;
        cr[0] += c1; ci[0] += s1;
        #pragma unroll
        for (int k = 1; k < NPTS; ++k) {
            float cn_ = ck * c1 - sk * s1;
            float sn_ = sk * c1 + ck * s1;
            ck = cn_; sk = sn_;
            cr[k] += ck; ci[k] += sk;
        }
    }
    #pragma unroll
    for (int i = 0; i < NPTS; ++i) {
        pecf[(size_t)((ch * NPTS + i) * 2 + 0) * KDIR + c] = cr[i];
        pecf[(size_t)((ch * NPTS + i) * 2 + 1) * KDIR + c] = ci[i];
    }
}

// K4: chunk reduce, one latency round: 544 blocks = 17 i x 16 grp x 2 halves.
__global__ __launch_bounds__(256) void ecf_p2a(const float* __restrict__ pecf,
                                               double* __restrict__ pec2) {
    const int b = blockIdx.x;
    const int i = b >> 5;                 // 0..16
    const int r = b & 31;
    const int g = r >> 1;                 // 0..15 (16 chunks each)
    const int half = r & 1;
    const int c = half * 256 + threadIdx.x;
    double sc = 0.0, ss = 0.0;
    #pragma unroll
    for (int k = 0; k < 16; ++k) {
        const int ch = g * 16 + k;
        sc += (double)pecf[(size_t)((ch * NPTS + i) * 2 + 0) * KDIR + c];
        ss += (double)pecf[(size_t)((ch * NPTS + i) * 2 + 1) * KDIR + c];
    }
    pec2[(size_t)((i * 16 + g) * 2 + 0) * KDIR + c] = sc;
    pec2[(size_t)((i * 16 + g) * 2 + 1) * KDIR + c] = ss;
}

// K5: finish: sum 16 groups (unrolled), integrand, block-reduce, atomic.
__global__ __launch_bounds__(256) void ecf_p2b(const double* __restrict__ pec2,
                                               float* __restrict__ out) {
    const int i = blockIdx.x >> 1;
    const int c = (blockIdx.x & 1) * 256 + threadIdx.x;
    double sc = 0.0, ss = 0.0;
    #pragma unroll
    for (int g = 0; g < 16; ++g) {
        sc += pec2[(size_t)((i * 16 + g) * 2 + 0) * KDIR + c];
        ss += pec2[(size_t)((i * 16 + g) * 2 + 1) * KDIR + c];
    }
    const double R = sc / (double)BATCH;
    const double I = ss / (double)BATCH;
    const double t = (2.0 / 17.0) * (double)(i + 1);
    const double tau = exp(-0.5 * t * t);
    const double w = (i == 0 || i == NPTS - 1) ? (1.0 / 17.0) : (2.0 / 17.0);
    const double dR = R - tau;
    double contrib = w * (dR * dR + I * I) / (double)KDIR;

    __shared__ double red[256];
    red[threadIdx.x] = contrib;
    __syncthreads();
    for (int s = 128; s > 0; s >>= 1) {
        if (threadIdx.x < s) red[threadIdx.x] += red[threadIdx.x + s];
        __syncthreads();
    }
    if (threadIdx.x == 0) atomicAdd(out, (float)red[0]);
}

// ---------------------------------------------------------------------------
extern "C" void kernel_launch(void* const* d_in, const int* in_sizes, int n_in,
                              void* d_out, int out_size, void* d_ws, size_t ws_size,
                              hipStream_t stream) {
    const float* emb = (const float*)d_in[0];   // (8192, 2048) fp32
    const float* dir = (const float*)d_in[1];   // (2048, 512) fp32
    float* out = (float*)d_out;

    char* ws = (char*)d_ws;
    // no aliasing needed anymore (A16 eliminated): total ~38.9 MB
    float*    proj = (float*)   (ws + 0);               // 16,777,216 B
    float*    pecf = (float*)   (ws + 16777216);        // 17,825,792 B
    double*   pec2 = (double*)  (ws + 34603008);        //  2,228,224 B
    _Float16* dT   = (_Float16*)(ws + 36831232);        //  2,097,152 B
    float*    pp   = (float*)   (ws + 38928384);        //      4,096 B

    norm_dT<<<KDIR, 256, 0, stream>>>(dir, dT, pp, out);
    gemm16<<<dim3(BATCH / 128, KDIR / 128), 256, 0, stream>>>(emb, dT, proj, pp);
    ecf_p1<<<512, 256, 0, stream>>>(proj, pp, pecf);
    ecf_p2a<<<544, 256, 0, stream>>>(pecf, pec2);
    ecf_p2b<<<34, 256, 0, stream>>>(pec2, out);
}